// Round 1
// baseline (317.929 us; speedup 1.0000x reference)
//
#include <hip/hip_runtime.h>

#define B_DIM 8
#define E_DIM 16
#define G_DIM 20000
#define P_DIM 512
#define P4    (P_DIM / 4)   // 128 float4 columns
#define NCHUNK 128          // g-chunks per e

// out[b,e,p] = bias[e,p]  (also clears the 0xAA poison)
__global__ __launch_bounds__(256) void bias_init_kernel(const float* __restrict__ bias,
                                                        float* __restrict__ out, int total) {
    int i = blockIdx.x * 256 + threadIdx.x;
    if (i < total) out[i] = bias[i % (E_DIM * P_DIM)];
}

__global__ __launch_bounds__(128) void masked_embed_kernel(const float* __restrict__ x,
                                                           const float* __restrict__ w,
                                                           const float* __restrict__ mask,
                                                           float* __restrict__ out) {
    const int p4 = threadIdx.x;        // 0..127 -> float4 column in P
    const int e  = blockIdx.y;

    const int gpc = (G_DIM + gridDim.x - 1) / gridDim.x;   // 157
    int gs = blockIdx.x * gpc;
    int ge = gs + gpc;
    if (ge > G_DIM) ge = G_DIM;

    const float4* __restrict__ wp =
        reinterpret_cast<const float4*>(w) + (size_t)e * G_DIM * P4;
    const float4* __restrict__ mp = reinterpret_cast<const float4*>(mask);

    float4 acc[B_DIM];
#pragma unroll
    for (int b = 0; b < B_DIM; ++b) acc[b] = make_float4(0.f, 0.f, 0.f, 0.f);

    for (int g = gs; g < ge; ++g) {
        float4 mv = mp[(size_t)g * P4 + p4];
        float4 wv = wp[(size_t)g * P4 + p4];
        float4 wm;
        wm.x = wv.x * mv.x;
        wm.y = wv.y * mv.y;
        wm.z = wv.z * mv.z;
        wm.w = wv.w * mv.w;
#pragma unroll
        for (int b = 0; b < B_DIM; ++b) {
            float xv = x[b * G_DIM + g];   // block-uniform -> s_load
            acc[b].x = fmaf(xv, wm.x, acc[b].x);
            acc[b].y = fmaf(xv, wm.y, acc[b].y);
            acc[b].z = fmaf(xv, wm.z, acc[b].z);
            acc[b].w = fmaf(xv, wm.w, acc[b].w);
        }
    }

    const int p = p4 * 4;
#pragma unroll
    for (int b = 0; b < B_DIM; ++b) {
        float* op = out + ((size_t)b * E_DIM + e) * P_DIM + p;
        atomicAdd(op + 0, acc[b].x);
        atomicAdd(op + 1, acc[b].y);
        atomicAdd(op + 2, acc[b].z);
        atomicAdd(op + 3, acc[b].w);
    }
}

extern "C" void kernel_launch(void* const* d_in, const int* in_sizes, int n_in,
                              void* d_out, int out_size, void* d_ws, size_t ws_size,
                              hipStream_t stream) {
    const float* x    = (const float*)d_in[0];   // [B, G]
    const float* w    = (const float*)d_in[1];   // [E, G, P]
    const float* bias = (const float*)d_in[2];   // [E, P]
    const float* mask = (const float*)d_in[3];   // [G, P]
    float* out = (float*)d_out;                  // [B, E, P] fp32

    const int total = B_DIM * E_DIM * P_DIM;     // 65536
    bias_init_kernel<<<dim3((total + 255) / 256), dim3(256), 0, stream>>>(bias, out, total);
    masked_embed_kernel<<<dim3(NCHUNK, E_DIM), dim3(128), 0, stream>>>(x, w, mask, out);
}

// Round 2
// 271.395 us; speedup vs baseline: 1.1715x; 1.1715x over previous
//
#include <hip/hip_runtime.h>

#define B_DIM 8
#define E_DIM 16
#define G_DIM 20000
#define P_DIM 512
#define P4    (P_DIM / 4)   // 128 float4 columns
#define NCHUNK 128          // g-chunks per e

// out[b,e,p] = bias[e,p]  (also clears the 0xAA poison)
__global__ __launch_bounds__(256) void bias_init_kernel(const float* __restrict__ bias,
                                                        float* __restrict__ out, int total) {
    int i = blockIdx.x * 256 + threadIdx.x;
    if (i < total) out[i] = bias[i % (E_DIM * P_DIM)];
}

#define MUL4(d, a, b) \
    d.x = a.x * b.x; d.y = a.y * b.y; d.z = a.z * b.z; d.w = a.w * b.w;

#define FMA4(acc, xv, wm) \
    acc.x = fmaf(xv, wm.x, acc.x); \
    acc.y = fmaf(xv, wm.y, acc.y); \
    acc.z = fmaf(xv, wm.z, acc.z); \
    acc.w = fmaf(xv, wm.w, acc.w);

__global__ __launch_bounds__(128) void masked_embed_kernel(const float* __restrict__ x,
                                                           const float* __restrict__ w,
                                                           const float* __restrict__ mask,
                                                           float* __restrict__ out) {
    const int p4 = threadIdx.x;        // 0..127 -> float4 column in P
    const int e  = blockIdx.y;

    const int gpc = (G_DIM + gridDim.x - 1) / gridDim.x;   // 157
    int gs = blockIdx.x * gpc;
    int ge = gs + gpc;
    if (ge > G_DIM) ge = G_DIM;

    const float4* __restrict__ wp =
        reinterpret_cast<const float4*>(w) + (size_t)e * G_DIM * P4;
    const float4* __restrict__ mp = reinterpret_cast<const float4*>(mask);

    // 8 NAMED accumulators -> guaranteed static register allocation
    float4 a0 = make_float4(0.f, 0.f, 0.f, 0.f), a1 = a0, a2 = a0, a3 = a0,
           a4 = a0, a5 = a0, a6 = a0, a7 = a0;

    int g = gs;
    // g unrolled x2: 4 vector loads (64 B/lane) in flight per iteration
    for (; g + 2 <= ge; g += 2) {
        const size_t i0 = (size_t)g * P4 + p4;
        const size_t i1 = i0 + P4;
        float4 m0 = mp[i0];
        float4 m1 = mp[i1];
        float4 w0 = wp[i0];
        float4 w1 = wp[i1];

        float x00 = x[0 * G_DIM + g], x01 = x[1 * G_DIM + g];
        float x02 = x[2 * G_DIM + g], x03 = x[3 * G_DIM + g];
        float x04 = x[4 * G_DIM + g], x05 = x[5 * G_DIM + g];
        float x06 = x[6 * G_DIM + g], x07 = x[7 * G_DIM + g];
        float x10 = x[0 * G_DIM + g + 1], x11 = x[1 * G_DIM + g + 1];
        float x12 = x[2 * G_DIM + g + 1], x13 = x[3 * G_DIM + g + 1];
        float x14 = x[4 * G_DIM + g + 1], x15 = x[5 * G_DIM + g + 1];
        float x16 = x[6 * G_DIM + g + 1], x17 = x[7 * G_DIM + g + 1];

        float4 wm0, wm1;
        MUL4(wm0, w0, m0);
        MUL4(wm1, w1, m1);

        FMA4(a0, x00, wm0); FMA4(a1, x01, wm0);
        FMA4(a2, x02, wm0); FMA4(a3, x03, wm0);
        FMA4(a4, x04, wm0); FMA4(a5, x05, wm0);
        FMA4(a6, x06, wm0); FMA4(a7, x07, wm0);

        FMA4(a0, x10, wm1); FMA4(a1, x11, wm1);
        FMA4(a2, x12, wm1); FMA4(a3, x13, wm1);
        FMA4(a4, x14, wm1); FMA4(a5, x15, wm1);
        FMA4(a6, x16, wm1); FMA4(a7, x17, wm1);
    }
    // tail (gpc=157 is odd)
    for (; g < ge; ++g) {
        const size_t i0 = (size_t)g * P4 + p4;
        float4 m0 = mp[i0];
        float4 w0 = wp[i0];
        float x00 = x[0 * G_DIM + g], x01 = x[1 * G_DIM + g];
        float x02 = x[2 * G_DIM + g], x03 = x[3 * G_DIM + g];
        float x04 = x[4 * G_DIM + g], x05 = x[5 * G_DIM + g];
        float x06 = x[6 * G_DIM + g], x07 = x[7 * G_DIM + g];
        float4 wm0;
        MUL4(wm0, w0, m0);
        FMA4(a0, x00, wm0); FMA4(a1, x01, wm0);
        FMA4(a2, x02, wm0); FMA4(a3, x03, wm0);
        FMA4(a4, x04, wm0); FMA4(a5, x05, wm0);
        FMA4(a6, x06, wm0); FMA4(a7, x07, wm0);
    }

    const int p = p4 * 4;
    float* ob = out + (size_t)e * P_DIM + p;
#define STORE4(acc, b) { \
        float* op = ob + (size_t)(b) * E_DIM * P_DIM; \
        atomicAdd(op + 0, acc.x); \
        atomicAdd(op + 1, acc.y); \
        atomicAdd(op + 2, acc.z); \
        atomicAdd(op + 3, acc.w); }
    STORE4(a0, 0) STORE4(a1, 1) STORE4(a2, 2) STORE4(a3, 3)
    STORE4(a4, 4) STORE4(a5, 5) STORE4(a6, 6) STORE4(a7, 7)
#undef STORE4
}

extern "C" void kernel_launch(void* const* d_in, const int* in_sizes, int n_in,
                              void* d_out, int out_size, void* d_ws, size_t ws_size,
                              hipStream_t stream) {
    const float* x    = (const float*)d_in[0];   // [B, G]
    const float* w    = (const float*)d_in[1];   // [E, G, P]
    const float* bias = (const float*)d_in[2];   // [E, P]
    const float* mask = (const float*)d_in[3];   // [G, P]
    float* out = (float*)d_out;                  // [B, E, P] fp32

    const int total = B_DIM * E_DIM * P_DIM;     // 65536
    bias_init_kernel<<<dim3((total + 255) / 256), dim3(256), 0, stream>>>(bias, out, total);
    masked_embed_kernel<<<dim3(NCHUNK, E_DIM), dim3(128), 0, stream>>>(x, w, mask, out);
}